// Round 11
// baseline (236.196 us; speedup 1.0000x reference)
//
#include <hip/hip_runtime.h>

// ---------------- problem constants (fixed by setup_inputs) ----------------
constexpr int B_ = 2, N_ = 8192, M_ = 8192, Dd = 64;
constexpr int TN = 128;              // n-rows per block (4 waves x 32 n each)
constexpr int TM = 64;               // ref rows per SUB-chunk
constexpr int SPLIT = 8;             // M-splits; blockIdx&7 pins split->XCD
constexpr int MCHUNK = M_ / SPLIT;   // 1024
constexpr int NCHUNKS = MCHUNK / (2 * TM); // 8 outer chunks of 128 rows
constexpr int NT = N_ / TN;          // 64
constexpr float LOG2E   = 1.4426950408889634f;
constexpr float SCALE_S = LOG2E / 64.0f;    //  dot/64    in log2 domain
constexpr float SCALE_N = -LOG2E / 128.0f;  // -|v|^2/128 in log2 domain

using s16x8  = __attribute__((ext_vector_type(8))) short;
using f32x16 = __attribute__((ext_vector_type(16))) float;
using f32x2v = __attribute__((ext_vector_type(2))) float;
using bf16x2 = __attribute__((ext_vector_type(2))) __bf16;

#if defined(__has_builtin)
#if __has_builtin(__builtin_amdgcn_exp2f)
#define EXP2(x) __builtin_amdgcn_exp2f(x)
#endif
#endif
#ifndef EXP2
#define EXP2(x) exp2f(x)
#endif

// f32 pair -> packed bf16 (RNE) via 2-wide vector fptrunc -> v_cvt_pk_bf16_f32.
__device__ __forceinline__ unsigned pk2(float lo, float hi) {
  f32x2v f;
  f[0] = lo;
  f[1] = hi;
  bf16x2 h = __builtin_convertvector(f, bf16x2);
  return __builtin_bit_cast(unsigned, h);
}
__device__ __forceinline__ f32x16 mfma32(s16x8 a, s16x8 b, f32x16 c) {
  return __builtin_amdgcn_mfma_f32_32x32x16_bf16(a, b, c, 0, 0, 0);
}
__device__ __forceinline__ float dot4(float4 f) {
  return f.x * f.x + f.y * f.y + f.z * f.z + f.w * f.w;
}
__device__ __forceinline__ float cload(const float* p) {  // device-coherent load
  return __hip_atomic_load(p, __ATOMIC_RELAXED, __HIP_MEMORY_SCOPE_AGENT);
}

// 32x32x16 layouts: A: row=lane&31, k=(lane>>5)*8+elem. B: col=lane&31, k same.
// C/D (m74/m101-verified): col=lane&31, row=(reg&3)+8*(reg>>2)+4*(lane>>5).
// P path (NO LDS), shfl_xor(.,32) redistribution, den lane-local: R9-proven.
// ldsYT swizzle (R4-proven): (d,m) at 16B chunk F=((m>>3)+2*(d>>4)+(d&7))&7, off m&7.
//
// THIS ROUND: fuse the division pass into this kernel (probe of the ~52us constant
// end-to-end minus msflash gap). After each block's atomics: fence+barrier, then a
// per-(bb,nt) completion counter; the LAST of the 8 split-blocks re-reads num/den
// via device-coherent loads (per-XCD L2 not coherent for plain loads) and writes
// out = num/den. No spins -> no deadlock, no dispatch-order assumption (G16-safe).

__global__ __launch_bounds__(256, 4) void msflash_kernel(
    const float* __restrict__ pts, const float* __restrict__ ref,
    float* __restrict__ num_acc, float* __restrict__ den_acc,
    unsigned* __restrict__ cnt, float* __restrict__ out) {
  __shared__ unsigned short ldsY[2][TM][72];   // QK A by-sub; X-stage [128][72] alias; O-scratch
  __shared__ unsigned short ldsYT[2][Dd][64];  // PV A (swizzled), per sub
  __shared__ float bm2[2][TM];                 // Y row norms per sub
  __shared__ float an2[TN];                    // X row norms (prologue only)
  __shared__ int lastblk;
  // total ~35.9 KB -> 4 blocks/CU

  const int tid  = threadIdx.x;
  const int w    = tid >> 6;
  const int lane = tid & 63;
  const int c32  = lane & 31;
  const int hi   = lane >> 5;

  const int s  = blockIdx.x & (SPLIT - 1);
  const int r  = blockIdx.x >> 3;
  const int bb = r / NT;
  const int nt_ = r % NT;
  const int n0 = nt_ * TN;
  const int m_begin = s * MCHUNK;

  // ---- staging thread mapping (Y): 64 rows x 4 threads x 16 d each ----
  const int rowl_s = tid >> 2, q_s = tid & 3;
  const float* ybase = ref + ((size_t)bb * M_ + m_begin + rowl_s) * Dd + q_s * 16;

  auto stage = [&](int sub, int sc) {  // load+convert 64-row sub-chunk sc -> slot sub
    const float* yp = ybase + (size_t)sc * TM * Dd;
    float4 a0 = ((const float4*)yp)[0];
    float4 a1 = ((const float4*)yp)[1];
    float4 a2 = ((const float4*)yp)[2];
    float4 a3 = ((const float4*)yp)[3];
    unsigned pkd[8] = {pk2(a0.x, a0.y), pk2(a0.z, a0.w), pk2(a1.x, a1.y), pk2(a1.z, a1.w),
                       pk2(a2.x, a2.y), pk2(a2.z, a2.w), pk2(a3.x, a3.y), pk2(a3.z, a3.w)};
    float sq = dot4(a0) + dot4(a1) + dot4(a2) + dot4(a3);
    sq += __shfl_xor(sq, 1);
    sq += __shfl_xor(sq, 2);
    if (q_s == 0) bm2[sub][rowl_s] = sq * SCALE_N;
    uint4* dv = (uint4*)&ldsY[sub][rowl_s][q_s * 16];
    dv[0] = make_uint4(pkd[0], pkd[1], pkd[2], pkd[3]);
    dv[1] = make_uint4(pkd[4], pkd[5], pkd[6], pkd[7]);
    const int tsw = (rowl_s >> 3) + 2 * q_s;
    const int mlo = rowl_s & 7;
#pragma unroll
    for (int j = 0; j < 8; j++) {
      const int d0 = q_s * 16 + 2 * j;
      const int c0 = (tsw + ((2 * j) & 7)) & 7;
      const int c1 = (tsw + ((2 * j + 1) & 7)) & 7;
      ldsYT[sub][d0][(c0 << 3) + mlo]     = (unsigned short)pkd[j];
      ldsYT[sub][d0 + 1][(c1 << 3) + mlo] = (unsigned short)(pkd[j] >> 16);
    }
  };

  // ---- prologue: X stage (fp32->bf16) into ldsY alias [128][72] + row norms ----
  unsigned short (*ldsX)[72] = (unsigned short (*)[72]) & ldsY[0][0][0];
  {
    const int rowl = tid >> 1, half = tid & 1;
    const float* gp = pts + ((size_t)bb * N_ + n0 + rowl) * Dd + half * 32;
    float sq = 0.f;
    unsigned pkd[16];
#pragma unroll
    for (int i = 0; i < 8; i++) {
      float4 f = ((const float4*)gp)[i];
      sq += dot4(f);
      pkd[2 * i + 0] = pk2(f.x, f.y);
      pkd[2 * i + 1] = pk2(f.z, f.w);
    }
    sq += __shfl_xor(sq, 1);
    if (half == 0) an2[rowl] = sq * SCALE_N;
    uint4* dv = (uint4*)&ldsX[rowl][half * 32];
#pragma unroll
    for (int i = 0; i < 4; i++)
      dv[i] = make_uint4(pkd[4 * i], pkd[4 * i + 1], pkd[4 * i + 2], pkd[4 * i + 3]);
  }
  __syncthreads();

  // X B-frags (col n = w*32+c32) + -|x|^2 term -> registers
  s16x8 bx[4];
#pragma unroll
  for (int k = 0; k < 4; k++)
    bx[k] = *(const s16x8*)&ldsX[w * 32 + c32][k * 16 + hi * 8];
  const float anr = an2[w * 32 + c32];

  f32x16 o0, o1;
#pragma unroll
  for (int i = 0; i < 16; i++) { o0[i] = 0.f; o1[i] = 0.f; }
  float dacc = 0.f;

  const int ytbase = hi + 2 * (c32 >> 4) + (c32 & 7);  // thread-const part of YT read F

  for (int c = 0; c < NCHUNKS; ++c) {
    __syncthreads();   // previous chunk's reads (and prologue bx reads) done
    stage(0, 2 * c);
    stage(1, 2 * c + 1);
    __syncthreads();   // both sub-chunks staged

#pragma unroll
    for (int sub = 0; sub < 2; sub++) {
#pragma unroll
      for (int t = 0; t < 2; t++) {
        // QK: S^T 32x32 tile (A = Y rows t*32+c32 of this sub, B = bx)
        f32x16 sf;
#pragma unroll
        for (int i = 0; i < 16; i++) sf[i] = 0.f;
#pragma unroll
        for (int k = 0; k < 4; k++) {
          s16x8 a = *(const s16x8*)&ldsY[sub][t * 32 + c32][k * 16 + hi * 8];
          sf = mfma32(a, bx[k], sf);
        }
        // exp2 + pack (C row m = t*32 + (reg&3)+8*(reg>>2)+4*hi)
        unsigned dw[8], sw[8];
#pragma unroll
        for (int rg = 0; rg < 4; rg++) {
          float4 bm = *(const float4*)&bm2[sub][t * 32 + 8 * rg + 4 * hi];
          float e0 = EXP2(sf[4 * rg + 0] * SCALE_S + (anr + bm.x));
          float e1 = EXP2(sf[4 * rg + 1] * SCALE_S + (anr + bm.y));
          float e2 = EXP2(sf[4 * rg + 2] * SCALE_S + (anr + bm.z));
          float e3 = EXP2(sf[4 * rg + 3] * SCALE_S + (anr + bm.w));
          dacc += (e0 + e1) + (e2 + e3);
          dw[2 * rg + 0] = pk2(e0, e1);
          dw[2 * rg + 1] = pk2(e2, e3);
        }
#pragma unroll
        for (int j = 0; j < 8; j++) sw[j] = __shfl_xor(dw[j], 32);
        // PV: per local kstep build P-frag in-reg, accumulate both d-tiles
#pragma unroll
        for (int kk = 0; kk < 2; kk++) {
          unsigned f0 = hi ? sw[4 * kk + 2] : dw[4 * kk + 0];
          unsigned f1 = hi ? sw[4 * kk + 3] : dw[4 * kk + 1];
          unsigned f2 = hi ? dw[4 * kk + 2] : sw[4 * kk + 0];
          unsigned f3 = hi ? dw[4 * kk + 3] : sw[4 * kk + 1];
          s16x8 pf = __builtin_bit_cast(s16x8, make_uint4(f0, f1, f2, f3));
          const int ks = 2 * t + kk;
          const int F0 = (2 * ks + ytbase) & 7;        // dtile 0
          const int F1 = (2 * ks + ytbase + 4) & 7;    // dtile 1 (4*dtile)
          s16x8 a0 = *(const s16x8*)&ldsYT[sub][c32][F0 * 8];
          s16x8 a1 = *(const s16x8*)&ldsYT[sub][32 + c32][F1 * 8];
          o0 = mfma32(a0, pf, o0);
          o1 = mfma32(a1, pf, o1);
        }
      }
    }
  }

  // ---- epilogue: accumulate this split's partials ----
  dacc += __shfl_xor(dacc, 32);   // full den[n=c32] in every lane
  __syncthreads();                // all waves done reading ldsY/ldsYT
  // O^T -> O transpose via wave-private scratch [32 n][36 d-pad] over ldsY alias
  float* sc = (float*)&ldsY[0][0][0] + (size_t)w * 1152;   // 4608 B per wave
  float* nb = num_acc + ((size_t)bb * N_ + n0 + w * 32) * Dd;
#pragma unroll
  for (int h = 0; h < 2; h++) {                  // d-tile halves
    const f32x16& oh = h ? o1 : o0;
#pragma unroll
    for (int rg = 0; rg < 4; rg++) {
      // d_local = 8*rg + 4*hi + g, n = c32
      *(float4*)&sc[c32 * 36 + 8 * rg + 4 * hi] =
          make_float4(oh[4 * rg + 0], oh[4 * rg + 1], oh[4 * rg + 2], oh[4 * rg + 3]);
    }
    // wave-private in-order LDS: read rows, coalesced atomics (2 n-rows x 32 d per instr)
#pragma unroll
    for (int rr = 0; rr < 16; rr++) {
      const int row = 2 * rr + hi;
      float v = sc[row * 36 + c32];
      atomicAdd(&nb[(size_t)row * Dd + h * 32 + c32], v);
    }
  }
  if (hi == 0)
    atomicAdd(&den_acc[(size_t)bb * N_ + n0 + w * 32 + c32], dacc);

  // ---- fused finalize: LAST split-block of this (bb,nt) group divides & stores ----
  __threadfence();     // release our atomics to device scope
  __syncthreads();     // whole block's atomics drained (vmcnt(0) before s_barrier)
  if (tid == 0)
    lastblk = (atomicAdd(&cnt[r], 1u) == SPLIT - 1);
  __syncthreads();
  if (lastblk) {
    __threadfence();   // acquire side
    const size_t gbase = (size_t)bb * N_ + n0;          // first of 128 rows
    const float* nbase = num_acc + gbase * Dd;
    float* obase = out + gbase * Dd;
#pragma unroll
    for (int j = 0; j < 8; j++) {
      const int i4 = j * 256 + tid;                     // float4 idx in [0,2048)
      const int row = i4 >> 4;                          // 16 float4 per 64-f row
      const float inv = 1.0f / cload(&den_acc[gbase + row]);
      const size_t fo = (size_t)i4 * 4;
      float x0 = cload(&nbase[fo + 0]);
      float x1 = cload(&nbase[fo + 1]);
      float x2 = cload(&nbase[fo + 2]);
      float x3 = cload(&nbase[fo + 3]);
      *(float4*)&obase[fo] = make_float4(x0 * inv, x1 * inv, x2 * inv, x3 * inv);
    }
  }
}

extern "C" void kernel_launch(void* const* d_in, const int* in_sizes, int n_in,
                              void* d_out, int out_size, void* d_ws, size_t ws_size,
                              hipStream_t stream) {
  const float* pts = (const float*)d_in[0];
  const float* ref = (const float*)d_in[1];
  float* out = (float*)d_out;
  float* num = (float*)d_ws;                       // [B,N,64] fp32 partial numerators
  float* den = num + (size_t)B_ * N_ * Dd;         // [B,N]    fp32 partial denominators
  unsigned* cnt = (unsigned*)(den + (size_t)B_ * N_);  // [B*NT] completion counters
  const size_t acc_bytes =
      ((size_t)B_ * N_ * Dd + (size_t)B_ * N_) * sizeof(float) +
      (size_t)B_ * NT * sizeof(unsigned);

  hipMemsetAsync(d_ws, 0, acc_bytes, stream);      // ws is re-poisoned 0xAA each launch
  msflash_kernel<<<dim3(B_ * NT * SPLIT), dim3(256), 0, stream>>>(pts, ref, num, den,
                                                                  cnt, out);
}

// Round 12
// 134.167 us; speedup vs baseline: 1.7605x; 1.7605x over previous
//
#include <hip/hip_runtime.h>

// ---------------- problem constants (fixed by setup_inputs) ----------------
constexpr int B_ = 2, N_ = 8192, M_ = 8192, Dd = 64;
constexpr int TN = 128;              // n-rows per block (4 waves x 32 n each)
constexpr int TM = 64;               // ref rows per SUB-chunk
constexpr int SPLIT = 8;             // M-splits; blockIdx&7 pins split->XCD
constexpr int MCHUNK = M_ / SPLIT;   // 1024
constexpr int NCHUNKS = MCHUNK / (2 * TM); // 8 outer chunks of 128 rows
constexpr int NT = N_ / TN;          // 64
constexpr float LOG2E   = 1.4426950408889634f;
constexpr float SCALE_S = LOG2E / 64.0f;    //  dot/64    in log2 domain
constexpr float SCALE_N = -LOG2E / 128.0f;  // -|v|^2/128 in log2 domain

using s16x8  = __attribute__((ext_vector_type(8))) short;
using f32x16 = __attribute__((ext_vector_type(16))) float;
using f32x2v = __attribute__((ext_vector_type(2))) float;
using bf16x2 = __attribute__((ext_vector_type(2))) __bf16;

#if defined(__has_builtin)
#if __has_builtin(__builtin_amdgcn_exp2f)
#define EXP2(x) __builtin_amdgcn_exp2f(x)
#endif
#endif
#ifndef EXP2
#define EXP2(x) exp2f(x)
#endif

// f32 pair -> packed bf16 (RNE) via 2-wide vector fptrunc -> v_cvt_pk_bf16_f32.
__device__ __forceinline__ unsigned pk2(float lo, float hi) {
  f32x2v f;
  f[0] = lo;
  f[1] = hi;
  bf16x2 h = __builtin_convertvector(f, bf16x2);
  return __builtin_bit_cast(unsigned, h);
}
__device__ __forceinline__ f32x16 mfma32(s16x8 a, s16x8 b, f32x16 c) {
  return __builtin_amdgcn_mfma_f32_32x32x16_bf16(a, b, c, 0, 0, 0);
}
__device__ __forceinline__ float dot4(float4 f) {
  return f.x * f.x + f.y * f.y + f.z * f.z + f.w * f.w;
}

// 32x32x16 layouts: A: row=lane&31, k=(lane>>5)*8+elem. B: col=lane&31, k same.
// C/D (m74/m101-verified): col=lane&31, row=(reg&3)+8*(reg>>2)+4*(lane>>5).
// P path (NO LDS), shfl_xor(.,32) redistribution, den lane-local: R9-proven.
// ldsYT swizzle (R4-proven): (d,m) at 16B chunk F=((m>>3)+2*(d>>4)+(d&7))&7, off m&7.
//
// Fused finalize v2 (R11 post-mortem: threadfence + SCALAR __hip_atomic_load tail
// cost ~143us). Protocol now: (1) NO fences -- __syncthreads() drains vmcnt(0), so
// all device-scope accumulation atomics (m20) are COMMITTED at the coherence point
// before tid0's counter atomicAdd is issued; (2) the last split-block re-reads
// num/den with explicit `sc0 sc1` VECTOR loads (cache-bypassing AND coalesced),
// one vmcnt(0) + sched_barrier(0) (rule #18) before use. No L2 wb/inv anywhere.

__global__ __launch_bounds__(256, 4) void msflash_kernel(
    const float* __restrict__ pts, const float* __restrict__ ref,
    float* __restrict__ num_acc, float* __restrict__ den_acc,
    unsigned* __restrict__ cnt, float* __restrict__ out) {
  __shared__ unsigned short ldsY[2][TM][72];   // QK A by-sub; X-stage [128][72] alias; O-scratch
  __shared__ unsigned short ldsYT[2][Dd][64];  // PV A (swizzled), per sub
  __shared__ float bm2[2][TM];                 // Y row norms per sub
  __shared__ float an2[TN];                    // X row norms (prologue only)
  __shared__ int lastblk;
  // total ~35.9 KB -> 4 blocks/CU

  const int tid  = threadIdx.x;
  const int w    = tid >> 6;
  const int lane = tid & 63;
  const int c32  = lane & 31;
  const int hi   = lane >> 5;

  const int s  = blockIdx.x & (SPLIT - 1);
  const int r  = blockIdx.x >> 3;
  const int bb = r / NT;
  const int nt_ = r % NT;
  const int n0 = nt_ * TN;
  const int m_begin = s * MCHUNK;

  // ---- staging thread mapping (Y): 64 rows x 4 threads x 16 d each ----
  const int rowl_s = tid >> 2, q_s = tid & 3;
  const float* ybase = ref + ((size_t)bb * M_ + m_begin + rowl_s) * Dd + q_s * 16;

  auto stage = [&](int sub, int sc) {  // load+convert 64-row sub-chunk sc -> slot sub
    const float* yp = ybase + (size_t)sc * TM * Dd;
    float4 a0 = ((const float4*)yp)[0];
    float4 a1 = ((const float4*)yp)[1];
    float4 a2 = ((const float4*)yp)[2];
    float4 a3 = ((const float4*)yp)[3];
    unsigned pkd[8] = {pk2(a0.x, a0.y), pk2(a0.z, a0.w), pk2(a1.x, a1.y), pk2(a1.z, a1.w),
                       pk2(a2.x, a2.y), pk2(a2.z, a2.w), pk2(a3.x, a3.y), pk2(a3.z, a3.w)};
    float sq = dot4(a0) + dot4(a1) + dot4(a2) + dot4(a3);
    sq += __shfl_xor(sq, 1);
    sq += __shfl_xor(sq, 2);
    if (q_s == 0) bm2[sub][rowl_s] = sq * SCALE_N;
    uint4* dv = (uint4*)&ldsY[sub][rowl_s][q_s * 16];
    dv[0] = make_uint4(pkd[0], pkd[1], pkd[2], pkd[3]);
    dv[1] = make_uint4(pkd[4], pkd[5], pkd[6], pkd[7]);
    const int tsw = (rowl_s >> 3) + 2 * q_s;
    const int mlo = rowl_s & 7;
#pragma unroll
    for (int j = 0; j < 8; j++) {
      const int d0 = q_s * 16 + 2 * j;
      const int c0 = (tsw + ((2 * j) & 7)) & 7;
      const int c1 = (tsw + ((2 * j + 1) & 7)) & 7;
      ldsYT[sub][d0][(c0 << 3) + mlo]     = (unsigned short)pkd[j];
      ldsYT[sub][d0 + 1][(c1 << 3) + mlo] = (unsigned short)(pkd[j] >> 16);
    }
  };

  // ---- prologue: X stage (fp32->bf16) into ldsY alias [128][72] + row norms ----
  unsigned short (*ldsX)[72] = (unsigned short (*)[72]) & ldsY[0][0][0];
  {
    const int rowl = tid >> 1, half = tid & 1;
    const float* gp = pts + ((size_t)bb * N_ + n0 + rowl) * Dd + half * 32;
    float sq = 0.f;
    unsigned pkd[16];
#pragma unroll
    for (int i = 0; i < 8; i++) {
      float4 f = ((const float4*)gp)[i];
      sq += dot4(f);
      pkd[2 * i + 0] = pk2(f.x, f.y);
      pkd[2 * i + 1] = pk2(f.z, f.w);
    }
    sq += __shfl_xor(sq, 1);
    if (half == 0) an2[rowl] = sq * SCALE_N;
    uint4* dv = (uint4*)&ldsX[rowl][half * 32];
#pragma unroll
    for (int i = 0; i < 4; i++)
      dv[i] = make_uint4(pkd[4 * i], pkd[4 * i + 1], pkd[4 * i + 2], pkd[4 * i + 3]);
  }
  __syncthreads();

  // X B-frags (col n = w*32+c32) + -|x|^2 term -> registers
  s16x8 bx[4];
#pragma unroll
  for (int k = 0; k < 4; k++)
    bx[k] = *(const s16x8*)&ldsX[w * 32 + c32][k * 16 + hi * 8];
  const float anr = an2[w * 32 + c32];

  f32x16 o0, o1;
#pragma unroll
  for (int i = 0; i < 16; i++) { o0[i] = 0.f; o1[i] = 0.f; }
  float dacc = 0.f;

  const int ytbase = hi + 2 * (c32 >> 4) + (c32 & 7);  // thread-const part of YT read F

  for (int c = 0; c < NCHUNKS; ++c) {
    __syncthreads();   // previous chunk's reads (and prologue bx reads) done
    stage(0, 2 * c);
    stage(1, 2 * c + 1);
    __syncthreads();   // both sub-chunks staged

#pragma unroll
    for (int sub = 0; sub < 2; sub++) {
#pragma unroll
      for (int t = 0; t < 2; t++) {
        // QK: S^T 32x32 tile (A = Y rows t*32+c32 of this sub, B = bx)
        f32x16 sf;
#pragma unroll
        for (int i = 0; i < 16; i++) sf[i] = 0.f;
#pragma unroll
        for (int k = 0; k < 4; k++) {
          s16x8 a = *(const s16x8*)&ldsY[sub][t * 32 + c32][k * 16 + hi * 8];
          sf = mfma32(a, bx[k], sf);
        }
        // exp2 + pack (C row m = t*32 + (reg&3)+8*(reg>>2)+4*hi)
        unsigned dw[8], sw[8];
#pragma unroll
        for (int rg = 0; rg < 4; rg++) {
          float4 bm = *(const float4*)&bm2[sub][t * 32 + 8 * rg + 4 * hi];
          float e0 = EXP2(sf[4 * rg + 0] * SCALE_S + (anr + bm.x));
          float e1 = EXP2(sf[4 * rg + 1] * SCALE_S + (anr + bm.y));
          float e2 = EXP2(sf[4 * rg + 2] * SCALE_S + (anr + bm.z));
          float e3 = EXP2(sf[4 * rg + 3] * SCALE_S + (anr + bm.w));
          dacc += (e0 + e1) + (e2 + e3);
          dw[2 * rg + 0] = pk2(e0, e1);
          dw[2 * rg + 1] = pk2(e2, e3);
        }
#pragma unroll
        for (int j = 0; j < 8; j++) sw[j] = __shfl_xor(dw[j], 32);
        // PV: per local kstep build P-frag in-reg, accumulate both d-tiles
#pragma unroll
        for (int kk = 0; kk < 2; kk++) {
          unsigned f0 = hi ? sw[4 * kk + 2] : dw[4 * kk + 0];
          unsigned f1 = hi ? sw[4 * kk + 3] : dw[4 * kk + 1];
          unsigned f2 = hi ? dw[4 * kk + 2] : sw[4 * kk + 0];
          unsigned f3 = hi ? dw[4 * kk + 3] : sw[4 * kk + 1];
          s16x8 pf = __builtin_bit_cast(s16x8, make_uint4(f0, f1, f2, f3));
          const int ks = 2 * t + kk;
          const int F0 = (2 * ks + ytbase) & 7;        // dtile 0
          const int F1 = (2 * ks + ytbase + 4) & 7;    // dtile 1 (4*dtile)
          s16x8 a0 = *(const s16x8*)&ldsYT[sub][c32][F0 * 8];
          s16x8 a1 = *(const s16x8*)&ldsYT[sub][32 + c32][F1 * 8];
          o0 = mfma32(a0, pf, o0);
          o1 = mfma32(a1, pf, o1);
        }
      }
    }
  }

  // ---- epilogue: accumulate this split's partials ----
  dacc += __shfl_xor(dacc, 32);   // full den[n=c32] in every lane
  __syncthreads();                // all waves done reading ldsY/ldsYT
  // O^T -> O transpose via wave-private scratch [32 n][36 d-pad] over ldsY alias
  float* sc = (float*)&ldsY[0][0][0] + (size_t)w * 1152;   // 4608 B per wave
  float* nb = num_acc + ((size_t)bb * N_ + n0 + w * 32) * Dd;
#pragma unroll
  for (int h = 0; h < 2; h++) {                  // d-tile halves
    const f32x16& oh = h ? o1 : o0;
#pragma unroll
    for (int rg = 0; rg < 4; rg++) {
      // d_local = 8*rg + 4*hi + g, n = c32
      *(float4*)&sc[c32 * 36 + 8 * rg + 4 * hi] =
          make_float4(oh[4 * rg + 0], oh[4 * rg + 1], oh[4 * rg + 2], oh[4 * rg + 3]);
    }
    // wave-private in-order LDS: read rows, coalesced atomics (2 n-rows x 32 d per instr)
#pragma unroll
    for (int rr = 0; rr < 16; rr++) {
      const int row = 2 * rr + hi;
      float v = sc[row * 36 + c32];
      atomicAdd(&nb[(size_t)row * Dd + h * 32 + c32], v);
    }
  }
  if (hi == 0)
    atomicAdd(&den_acc[(size_t)bb * N_ + n0 + w * 32 + c32], dacc);

  // ---- fused finalize: LAST split-block of this (bb,nt) group divides & stores ----
  __syncthreads();     // drains vmcnt(0) -> all our device-scope atomics committed
  if (tid == 0)
    lastblk = (atomicAdd(&cnt[r], 1u) == SPLIT - 1);   // device-scope (m20), no fence
  __syncthreads();
  if (lastblk) {
    const size_t gbase = (size_t)bb * N_ + n0;          // first of 128 rows
    const float* nbase = num_acc + gbase * Dd;
    float* obase = out + gbase * Dd;
    float4 xv[8];
    float  dv[8];
#pragma unroll
    for (int j = 0; j < 8; j++) {   // coalesced cache-BYPASSING vector loads
      const float* ap = &nbase[(size_t)(j * 256 + tid) * 4];
      asm volatile("global_load_dwordx4 %0, %1, off sc0 sc1"
                   : "=v"(xv[j]) : "v"(ap));
    }
#pragma unroll
    for (int j = 0; j < 8; j++) {
      const float* dp = &den_acc[gbase + ((j * 256 + tid) >> 4)];
      asm volatile("global_load_dword %0, %1, off sc0 sc1"
                   : "=v"(dv[j]) : "v"(dp));
    }
    asm volatile("s_waitcnt vmcnt(0)" ::: "memory");
    __builtin_amdgcn_sched_barrier(0);   // rule #18: keep consumers below the wait
#pragma unroll
    for (int j = 0; j < 8; j++) {
      const float inv = 1.0f / dv[j];
      *(float4*)&obase[(size_t)(j * 256 + tid) * 4] =
          make_float4(xv[j].x * inv, xv[j].y * inv, xv[j].z * inv, xv[j].w * inv);
    }
  }
}

extern "C" void kernel_launch(void* const* d_in, const int* in_sizes, int n_in,
                              void* d_out, int out_size, void* d_ws, size_t ws_size,
                              hipStream_t stream) {
  const float* pts = (const float*)d_in[0];
  const float* ref = (const float*)d_in[1];
  float* out = (float*)d_out;
  float* num = (float*)d_ws;                       // [B,N,64] fp32 partial numerators
  float* den = num + (size_t)B_ * N_ * Dd;         // [B,N]    fp32 partial denominators
  unsigned* cnt = (unsigned*)(den + (size_t)B_ * N_);  // [B*NT] completion counters
  const size_t acc_bytes =
      ((size_t)B_ * N_ * Dd + (size_t)B_ * N_) * sizeof(float) +
      (size_t)B_ * NT * sizeof(unsigned);

  hipMemsetAsync(d_ws, 0, acc_bytes, stream);      // ws is re-poisoned 0xAA each launch
  msflash_kernel<<<dim3(B_ * NT * SPLIT), dim3(256), 0, stream>>>(pts, ref, num, den,
                                                                  cnt, out);
}